// Round 14
// baseline (260.848 us; speedup 1.0000x reference)
//
#include <hip/hip_runtime.h>
#include <math.h>

typedef short bf16x8 __attribute__((ext_vector_type(8)));
typedef float f32x4 __attribute__((ext_vector_type(4)));
typedef int   i32x4 __attribute__((ext_vector_type(4)));

#define HH 8
#define NN 4096
#define DIP 256   // ip(240) + s(16) as int8, no pad
#define DDX 256   // qdx bf16: [hi|hi | mid|lo | mid32-47+16z | hi32-47+16z]
#define DKM 192   // kmx bf16: [mid | lo | hi | hi]
#define DV 272
#define BN 64
#define NT (NN/BN)

typedef const __attribute__((address_space(1))) unsigned int* gp_t;
typedef __attribute__((address_space(3))) unsigned int* lp_t;
__device__ __forceinline__ void gload16(const void* g, void* l) {
    __builtin_amdgcn_global_load_lds((gp_t)g, (lp_t)l, 16, 0, 0);
}

__device__ __forceinline__ unsigned short f2bf(float f) {
    unsigned int u = __float_as_uint(f);
    u = (u + 0x7fffu + ((u >> 16) & 1u)) >> 16;   // RNE
    return (unsigned short)u;
}
__device__ __forceinline__ float bf2f(unsigned short h) {
    return __uint_as_float(((unsigned int)h) << 16);
}
__device__ __forceinline__ float fexp2(float x) {   // 2^x, single v_exp_f32
    float r;
    asm("v_exp_f32 %0, %1" : "=v"(r) : "v"(x));
    return r;
}
__device__ __forceinline__ signed char q8(float x) {  // i8 quant, scale 127/6 (±6 sigma)
    int v = __float2int_rn(x * 21.1666667f);
    v = v < -127 ? -127 : (v > 127 ? 127 : v);
    return (signed char)v;
}

#define MFMA16(A,B,C) __builtin_amdgcn_mfma_f32_16x16x32_bf16((A),(B),(C),0,0,0)
#define MFMAI8(A,B,C) __builtin_amdgcn_mfma_i32_16x16x64_i8((A),(B),(C),0,0,0)

// ---- stage 1a: features. fip[256] = ip+s as i8. fdx bf16: Q-mode 256 / K-mode 192 ----
__global__ void feat_kernel(const float* __restrict__ mv,
                            const float* __restrict__ sv,
                            const float* __restrict__ basis,
                            float scale, int qmode,
                            signed char* __restrict__ fip,
                            unsigned short* __restrict__ fdx)
{
    __shared__ float sb[150];
    int t = threadIdx.x;
    if (t < 150) sb[t] = basis[t];
    __syncthreads();
    int row = blockIdx.x * 32 + (t >> 3);   // (h*4096+n)
    int c = t & 7;
    const float* m = mv + (size_t)row * 256 + c * 32;
    float f[32];
    #pragma unroll
    for (int i = 0; i < 8; ++i) {
        float4 v = ((const float4*)m)[i];
        f[i*4+0] = v.x; f[i*4+1] = v.y; f[i*4+2] = v.z; f[i*4+3] = v.w;
    }
    signed char* ip = fip + (size_t)row * DIP;
    unsigned short* dx = fdx + (size_t)row * (qmode ? DDX : DKM);
    #pragma unroll
    for (int j = 0; j < 30; ++j)
        ip[c*30 + j] = q8(f[1+j]);
    if (c < 2) {
        #pragma unroll
        for (int i = 0; i < 8; ++i)
            ip[240 + c*8 + i] = q8(sv[(size_t)row*16 + c*8 + i]);
    }
    float nn = 1.0f / sqrtf(f[5]*f[5] + 0.001f);
    float tn[5];
    #pragma unroll
    for (int x = 0; x < 5; ++x) tn[x] = f[1+x] * nn;
    #pragma unroll
    for (int z = 0; z < 6; ++z) {
        float acc = 0.f;
        #pragma unroll
        for (int x = 0; x < 5; ++x) {
            #pragma unroll
            for (int y = 0; y < 5; ++y)
                acc = fmaf(sb[(x*5+y)*6 + z] * tn[x], tn[y], acc);
        }
        acc *= scale;
        unsigned short hi = f2bf(acc);
        float r1 = acc - bf2f(hi);
        unsigned short mi = f2bf(r1);
        float r2 = r1 - bf2f(mi);
        unsigned short lo = f2bf(r2);
        int cz = c*6 + z;
        if (qmode) {
            dx[cz]      = hi;  dx[48 + cz]  = hi;
            dx[96 + cz] = mi;  dx[144 + cz] = lo;
            if (cz < 16) { dx[208 + cz] = 0; dx[240 + cz] = 0; }
            if (cz >= 32) { dx[160 + cz] = mi; dx[192 + cz] = hi; }
        } else {
            dx[cz]      = mi;  dx[48 + cz]  = lo;
            dx[96 + cz] = hi;  dx[144 + cz] = hi;
        }
    }
}

// ---- stage 1b: V -> transposed bf16 [8][272][4096] ----
__global__ void vtrans_kernel(const float* __restrict__ vmv,
                              const float* __restrict__ vs,
                              unsigned short* __restrict__ dst)
{
    __shared__ unsigned short tile[64][DV];
    int blk = blockIdx.x;
    int h = blk >> 6;
    int n0 = (blk & 63) << 6;
    int t = threadIdx.x;
    #pragma unroll
    for (int it = 0; it < 16; ++it) {
        int v = t + it*256;
        int r = v >> 6;
        int sg = v & 63;
        float4 x = *(const float4*)(vmv + ((size_t)(h*NN + n0 + r))*256 + sg*4);
        tile[r][sg*4+0] = f2bf(x.x);
        tile[r][sg*4+1] = f2bf(x.y);
        tile[r][sg*4+2] = f2bf(x.z);
        tile[r][sg*4+3] = f2bf(x.w);
    }
    #pragma unroll
    for (int it = 0; it < 4; ++it) {
        int v = t + it*256;
        int r = v >> 4;
        int si = v & 15;
        tile[r][256 + si] = f2bf(vs[((size_t)(h*NN + n0 + r))*16 + si]);
    }
    __syncthreads();
    #pragma unroll
    for (int it = 0; it < 17; ++it) {
        int v = t + it*256;
        int dd = v >> 4;
        int sg = v & 15;
        ushort4 o;
        o.x = tile[sg*4+0][dd];
        o.y = tile[sg*4+1][dd];
        o.z = tile[sg*4+2][dd];
        o.w = tile[sg*4+3][dd];
        *(ushort4*)(dst + ((size_t)(h*DV + dd))*NN + n0 + sg*4) = o;
    }
}

// ---- stage 2: flash attention, BN=64, i8 ip-QKT, PV dim-split across wave pairs ----
__global__ __launch_bounds__(512, 1)
void attn_kernel(const signed char*    __restrict__ Qip,
                 const unsigned short* __restrict__ Qdx,
                 const signed char*    __restrict__ Kip,
                 const unsigned short* __restrict__ Kmx,
                 const unsigned short* __restrict__ Vt,
                 float* __restrict__ out)
{
    // bytes: kt 2x16384 [0,32768) | kmx 2x24576 [32768,81920) | vt 34816 [81920,116736)
    //        pb 16384 [116736,133120) | alpha 512 [133120,133632) | lsum 512 [133632,134144)
    __shared__ __align__(128) unsigned short smem[67072];   // 134,144 B

    int blk = blockIdx.x;
    int sbk = ((blk & 7) << 5) | (blk >> 3);   // grid 256, bijective XCD swizzle; XCD x = head x
    int h = sbk >> 5;
    int q0 = (sbk & 31) * 128;
    int tid = threadIdx.x;
    int w = tid >> 6;
    int wp = w ^ 4;                            // partner wave
    int kh = w >> 2;                           // dim-half: 0 -> ct 0..8, 1 -> ct 9..16
    int lane = tid & 63;
    int l15 = lane & 15;
    int l4 = lane >> 4;
    int l7l = l15 & 3;
    int l7h = (l15 >> 2) & 1;
    int x7 = l15 & 7;

    // Q ip fragments: i8, B-operand (col=q=l15, k=l4*16+e), 4 K=64 steps
    const signed char* qipr = Qip + (size_t)(h*NN + q0 + w*16 + l15) * DIP + l4*16;
    i32x4 qip[4];
    #pragma unroll
    for (int s = 0; s < 4; ++s) qip[s] = *(const i32x4*)(qipr + s*64);
    // Q dist fragments: bf16 (dup-block scheme)
    const unsigned short* qdxr = Qdx + (size_t)(h*NN + q0 + w*16 + l15) * DDX + l4*8;
    bf16x8 qdx[8];
    #pragma unroll
    for (int ks = 0; ks < 8; ++ks) qdx[ks] = *(const bf16x8*)(qdxr + ks*32);

    // LDS read bases (bytes)
    int cl16 = (l4 ^ l7l) * 16;
    int mA  = l15*384 + cl16 + l7h*64;
    int mB  = l15*384 + cl16 + 64 - l7h*64;
    int kti[4];
    #pragma unroll
    for (int s = 0; s < 4; ++s)
        kti[s] = l15*256 + (((s*4 + l4) ^ x7) << 4);
    int vb0 = (l15>>1)*256 + ((((l15&1)*8 + l4) ^ (l15>>1)) << 4);
    int vb1 = (l15>>1)*256 + ((((l15&1)*8 + 4 + l4) ^ (l15>>1)) << 4);
    // P regions (row = q-index l15 within set, seg swizzle by row&7 -> any wave can read)
    int pbW = 116736 + w*2048 + l15*128;
    int pbP = 116736 + wp*2048 + l15*128;
    int pw[4];
    #pragma unroll
    for (int kt4 = 0; kt4 < 4; ++kt4)
        pw[kt4] = pbW + (((kt4*2 + (l4>>1)) ^ x7) << 4) + ((l4&1) << 3);
    int prO0 = pbW + ((l4 ^ x7) << 4);
    int prO1 = pbW + (((4+l4) ^ x7) << 4);
    int prP0 = pbP + ((l4 ^ x7) << 4);
    int prP1 = pbP + (((4+l4) ^ x7) << 4);
    int awr = 133120 + w*64 + l15*4;      // alpha write (l4==0 lanes)
    int ard = 133120 + wp*64 + l4*16;     // partner alpha read (f32x4, 16-lane bcast)
    int lwr = 133632 + w*64 + l15*4;
    int lrd = 133632 + wp*64 + l4*16;

    // DMA source offsets, loop-invariant
    int kts0, kts1;                       // Kip bytes
    { int idx = tid;       int r_ = idx>>4, sg_ = idx&15; kts0 = r_*256 + ((sg_ ^ (r_&7))<<4); }
    { int idx = tid+512;   int r_ = idx>>4, sg_ = idx&15; kts1 = r_*256 + ((sg_ ^ (r_&7))<<4); }
    int kms0, kms1, kms2;                 // Kmx ush
#define KMFL(SLOT, DST) { int r_ = (SLOT)/24, fp_ = (SLOT)%24; \
    int g_ = fp_>>3, po_ = fp_&7; \
    int pl_ = ((((po_>>2)&1) ^ ((r_>>2)&1)) << 2) | ((po_&3) ^ (r_&3)); \
    DST = r_*DKM + (g_*8 + pl_)*8; }
    KMFL(tid, kms0) KMFL(tid+512, kms1) KMFL(tid+1024, kms2)
#undef KMFL
    int vts0, vts1, vts2, vts3, vts4;     // Vt ush
#define VTF(SLOT, DST) { int ch_ = (SLOT)>>4, ps_ = (SLOT)&15; int ls_ = ps_ ^ (ch_&7); \
    DST = (ch_*2 + (ls_>>3))*NN + (ls_&7)*8; }
    VTF(tid, vts0) VTF(tid+512, vts1) VTF(tid+1024, vts2) VTF(tid+1536, vts3) VTF(tid+2048, vts4)
#undef VTF

    const signed char*    kiph = Kip + (size_t)h*NN*DIP;
    const unsigned short* kmxh = Kmx + (size_t)h*NN*DKM;
    const unsigned short* vh   = Vt  + (size_t)h*DV*NN;

    f32x4 zero = {0.f, 0.f, 0.f, 0.f};
    i32x4 zi = {0, 0, 0, 0};
    f32x4 oacc[9][2];                     // [own dim-half tile][q-set: 0=own wave, 1=partner]
    #pragma unroll
    for (int i = 0; i < 9; ++i) { oacc[i][0] = zero; oacc[i][1] = zero; }
    float mreg = -__builtin_inff();
    float lreg = 0.f;
    const float F = 0.08274443827037988f * (6.0f/127.0f) * (6.0f/127.0f);

#define ISSUE_K(TILE, BUF) do { \
    const signed char* ks_ = kiph + (size_t)(TILE)*BN*DIP; \
    const unsigned short* ms_ = kmxh + (size_t)(TILE)*BN*DKM; \
    char* ktd_ = (char*)smem + (BUF)*16384; \
    char* kmd_ = (char*)smem + 32768 + (BUF)*24576; \
    gload16(ks_ + kts0, ktd_ + tid*16); \
    gload16(ks_ + kts1, ktd_ + (tid+512)*16); \
    gload16(ms_ + kms0, kmd_ + tid*16); \
    gload16(ms_ + kms1, kmd_ + (tid+512)*16); \
    gload16(ms_ + kms2, kmd_ + (tid+1024)*16); \
} while (0)

#define ISSUE_V(TILE) do { \
    const unsigned short* vs_ = vh + (TILE)*BN; \
    char* vtd_ = (char*)smem + 81920; \
    gload16(vs_ + vts0, vtd_ + tid*16); \
    gload16(vs_ + vts1, vtd_ + (tid+512)*16); \
    gload16(vs_ + vts2, vtd_ + (tid+1024)*16); \
    gload16(vs_ + vts3, vtd_ + (tid+1536)*16); \
    if (tid < 128) gload16(vs_ + vts4, vtd_ + (tid+2048)*16); \
} while (0)

    ISSUE_K(0, 0);
    int cur = 0;
    #pragma unroll 1
    for (int t = 0; t < NT; ++t) {
        ISSUE_V(t);                          // vt free: BAR3(t-1) passed
        if (t < NT-1) {
            ISSUE_K(t+1, cur^1);
            if (w < 2) asm volatile("s_waitcnt vmcnt(10)" ::: "memory");
            else       asm volatile("s_waitcnt vmcnt(9)"  ::: "memory");
        } else {
            if (w < 2) asm volatile("s_waitcnt vmcnt(5)" ::: "memory");
            else       asm volatile("s_waitcnt vmcnt(4)" ::: "memory");
        }
        __builtin_amdgcn_sched_barrier(0);
        __builtin_amdgcn_s_barrier();        // BAR1: K tile t visible
        __builtin_amdgcn_sched_barrier(0);

        const char* ktb = (const char*)smem + cur*16384;
        const char* kmb = (const char*)smem + 32768 + cur*24576;

        f32x4 sf[4];
        i32x4 si[4];
        __builtin_amdgcn_s_setprio(1);
        #pragma unroll
        for (int kt4 = 0; kt4 < 4; ++kt4) {
            const char* kb = ktb + kt4*4096;
            i32x4 a = zi;
            a = MFMAI8(*(const i32x4*)(kb + kti[0]), qip[0], a);
            a = MFMAI8(*(const i32x4*)(kb + kti[1]), qip[1], a);
            a = MFMAI8(*(const i32x4*)(kb + kti[2]), qip[2], a);
            a = MFMAI8(*(const i32x4*)(kb + kti[3]), qip[3], a);
            si[kt4] = a;
            const char* kk = kmb + kt4*6144;
            bf16x8 ka0 = *(const bf16x8*)(kk + mA);
            bf16x8 ka1 = *(const bf16x8*)(kk + mB);
            bf16x8 ka2 = *(const bf16x8*)(kk + mA + 128);
            bf16x8 kb0 = *(const bf16x8*)(kk + mB + 128);
            bf16x8 kb1 = *(const bf16x8*)(kk + mA + 256);
            bf16x8 kb2 = *(const bf16x8*)(kk + mB + 256);
            f32x4 d = zero;
            d = MFMA16(ka0, qdx[0], d);
            d = MFMA16(ka1, qdx[1], d);
            d = MFMA16(ka2, qdx[2], d);
            d = MFMA16(kb0, qdx[3], d);
            d = MFMA16(kb1, qdx[4], d);
            d = MFMA16(kb2, qdx[5], d);
            d = MFMA16(ka0, qdx[3], d);
            d = MFMA16(ka1, qdx[6], d);
            d = MFMA16(kb0, qdx[0], d);
            d = MFMA16(kb1, qdx[7], d);
            sf[kt4] = d;
        }
        __builtin_amdgcn_s_setprio(0);

        // merge i8 + dist scores
        f32x4 sn[4];
        #pragma unroll
        for (int kt4 = 0; kt4 < 4; ++kt4) {
            sn[kt4][0] = sf[kt4][0] + F * (float)si[kt4][0];
            sn[kt4][1] = sf[kt4][1] + F * (float)si[kt4][1];
            sn[kt4][2] = sf[kt4][2] + F * (float)si[kt4][2];
            sn[kt4][3] = sf[kt4][3] + F * (float)si[kt4][3];
        }

        // online softmax over 64 keys, per-lane q=l15; defer-max THR=8 (log2 units)
        float pm = fmaxf(
            fmaxf(fmaxf(fmaxf(sn[0][0], sn[0][1]), fmaxf(sn[0][2], sn[0][3])),
                  fmaxf(fmaxf(sn[1][0], sn[1][1]), fmaxf(sn[1][2], sn[1][3]))),
            fmaxf(fmaxf(fmaxf(sn[2][0], sn[2][1]), fmaxf(sn[2][2], sn[2][3])),
                  fmaxf(fmaxf(sn[3][0], sn[3][1]), fmaxf(sn[3][2], sn[3][3]))));
        pm = fmaxf(pm, __shfl_xor(pm, 16, 64));
        pm = fmaxf(pm, __shfl_xor(pm, 32, 64));
        float al = 1.0f;
        if (!__all(pm <= mreg + 8.0f)) {
            float mnew = fmaxf(mreg, pm);
            al = fexp2(mreg - mnew);            // 0 on first tile
            mreg = mnew;
            lreg *= al;
            float a0 = __shfl(al, l4*4+0, 64);
            float a1 = __shfl(al, l4*4+1, 64);
            float a2 = __shfl(al, l4*4+2, 64);
            float a3 = __shfl(al, l4*4+3, 64);
            #pragma unroll
            for (int i = 0; i < 9; ++i) {
                oacc[i][0][0] *= a0; oacc[i][0][1] *= a1;
                oacc[i][0][2] *= a2; oacc[i][0][3] *= a3;
            }
        }
        char* pbp = (char*)smem;
        if (l4 == 0) *(float*)(pbp + awr) = al;  // alpha for partner (1.0 if no rescale)
        #pragma unroll
        for (int kt4 = 0; kt4 < 4; ++kt4) {
            float p0 = fexp2(sn[kt4][0] - mreg), p1 = fexp2(sn[kt4][1] - mreg);
            float p2 = fexp2(sn[kt4][2] - mreg), p3 = fexp2(sn[kt4][3] - mreg);
            lreg += (p0 + p1) + (p2 + p3);
            unsigned r01, r23;
            asm("v_cvt_pk_bf16_f32 %0, %1, %2" : "=v"(r01) : "v"(p0), "v"(p1));
            asm("v_cvt_pk_bf16_f32 %0, %1, %2" : "=v"(r23) : "v"(p2), "v"(p3));
            unsigned long long pk = ((unsigned long long)r23 << 32) | (unsigned long long)r01;
            *(unsigned long long*)(pbp + pw[kt4]) = pk;
        }

        // drain P/alpha ds_writes + V(t) DMA before the exchange barrier
        asm volatile("s_waitcnt lgkmcnt(0)" ::: "memory");
        if (t < NT-1) asm volatile("s_waitcnt vmcnt(5)" ::: "memory");
        else          asm volatile("s_waitcnt vmcnt(0)" ::: "memory");
        __builtin_amdgcn_sched_barrier(0);
        __builtin_amdgcn_s_barrier();        // BAR2: V tile + P/alpha of both waves ready
        __builtin_amdgcn_sched_barrier(0);

        // PV dim-split: own 9|8 dim-tiles, q-sets {w, w^4}, full 64 keys
        {
            f32x4 ap = *(const f32x4*)(pbp + ard);   // partner alphas for rows l4*4..+3
            #pragma unroll
            for (int i = 0; i < 9; ++i) {
                oacc[i][1][0] *= ap[0]; oacc[i][1][1] *= ap[1];
                oacc[i][1][2] *= ap[2]; oacc[i][1][3] *= ap[3];
            }
            bf16x8 paO0 = *(const bf16x8*)(pbp + prO0);
            bf16x8 paO1 = *(const bf16x8*)(pbp + prO1);
            bf16x8 paP0 = *(const bf16x8*)(pbp + prP0);
            bf16x8 paP1 = *(const bf16x8*)(pbp + prP1);
            const char* vtb = (const char*)smem + 81920;
            __builtin_amdgcn_s_setprio(1);
            #pragma unroll
            for (int i = 0; i < 9; ++i) {
                if (i < 8 || kh == 0) {
                    int ct = kh*9 + i;
                    bf16x8 bv0 = *(const bf16x8*)(vtb + ct*2048 + vb0);
                    bf16x8 bv1 = *(const bf16x8*)(vtb + ct*2048 + vb1);
                    oacc[i][0] = MFMA16(paO0, bv0, oacc[i][0]);
                    oacc[i][0] = MFMA16(paO1, bv1, oacc[i][0]);
                    oacc[i][1] = MFMA16(paP0, bv0, oacc[i][1]);
                    oacc[i][1] = MFMA16(paP1, bv1, oacc[i][1]);
                }
            }
            __builtin_amdgcn_s_setprio(0);
        }
        __builtin_amdgcn_s_barrier();        // BAR3: all waves done reading vt/pb
        __builtin_amdgcn_sched_barrier(0);
        cur ^= 1;
    }
#undef ISSUE_K
#undef ISSUE_V

    // epilogue: reduce own l, exchange with partner, scatter own dim-half for both q-sets
    float lf = lreg;
    lf += __shfl_xor(lf, 16, 64);
    lf += __shfl_xor(lf, 32, 64);
    char* pbp = (char*)smem;
    if (l4 == 0) *(float*)(pbp + lwr) = lf;
    asm volatile("s_waitcnt lgkmcnt(0)" ::: "memory");
    __builtin_amdgcn_sched_barrier(0);
    __builtin_amdgcn_s_barrier();
    __builtin_amdgcn_sched_barrier(0);
    f32x4 lp = *(const f32x4*)(pbp + lrd);

    const size_t mv_total = (size_t)HH * NN * 256;
    #pragma unroll
    for (int j = 0; j < 4; ++j) {
        float invO = 1.0f / __shfl(lf, l4*4 + j, 64);
        float invP = 1.0f / lp[j];
        int qO = q0 + w*16 + l4*4 + j;
        int qP = q0 + wp*16 + l4*4 + j;
        float* poO = out + ((size_t)h*NN + qO) * 256 + l15;
        float* poP = out + ((size_t)h*NN + qP) * 256 + l15;
        #pragma unroll
        for (int i = 0; i < 9; ++i) {
            if (i < 8 || kh == 0) {
                int ct = kh*9 + i;
                if (ct < 16) {
                    poO[ct*16] = oacc[i][0][j] * invO;
                    poP[ct*16] = oacc[i][1][j] * invP;
                } else {
                    out[mv_total + ((size_t)h*NN + qO)*16 + l15] = oacc[i][0][j] * invO;
                    out[mv_total + ((size_t)h*NN + qP)*16 + l15] = oacc[i][1][j] * invP;
                }
            }
        }
    }
}

extern "C" void kernel_launch(void* const* d_in, const int* in_sizes, int n_in,
                              void* d_out, int out_size, void* d_ws, size_t ws_size,
                              hipStream_t stream)
{
    const float* q_mv = (const float*)d_in[0];
    const float* k_mv = (const float*)d_in[1];
    const float* v_mv = (const float*)d_in[2];
    const float* q_s  = (const float*)d_in[3];
    const float* k_s  = (const float*)d_in[4];
    const float* v_s  = (const float*)d_in[5];
    const float* basis_q = (const float*)d_in[6];
    const float* basis_k = (const float*)d_in[7];
    float* out = (float*)d_out;

    signed char* qip8 = (signed char*)d_ws;                         // [8][4096][256] i8
    signed char* kip8 = qip8 + (size_t)HH*NN*DIP;                   // [8][4096][256] i8
    unsigned short* qdx = (unsigned short*)(kip8 + (size_t)HH*NN*DIP); // [8][4096][256] bf16
    unsigned short* kmx = qdx + (size_t)HH*NN*DDX;                  // [8][4096][192] bf16
    unsigned short* vt  = kmx + (size_t)HH*NN*DKM;                  // [8][272][4096] bf16
    // total ws use: ~64.1 MB

    // 1/sqrt(304) * log2(e): dist features carry it; ip carries it via F in-kernel
    const float qscale = 0.08274443827037988f;

    feat_kernel<<<dim3(1024), dim3(256), 0, stream>>>(q_mv, q_s, basis_q, qscale, 1, qip8, qdx);
    feat_kernel<<<dim3(1024), dim3(256), 0, stream>>>(k_mv, k_s, basis_k, 1.0f,   0, kip8, kmx);
    vtrans_kernel<<<dim3(512), dim3(256), 0, stream>>>(v_mv, v_s, vt);
    attn_kernel<<<dim3(256), dim3(512), 0, stream>>>(qip8, qdx, kip8, kmx, vt, out);
}